// Round 5
// baseline (182.114 us; speedup 1.0000x reference)
//
#include <hip/hip_runtime.h>

#define TT   2048
#define WIN  512

typedef unsigned short u16;
typedef unsigned long long u64;
typedef __bf16 bf16x8 __attribute__((ext_vector_type(8)));
typedef float  f32x4  __attribute__((ext_vector_type(4)));

__device__ __forceinline__ float bf2f(u16 u){
  unsigned v = ((unsigned)u) << 16;
  return __builtin_bit_cast(float, v);
}
__device__ __forceinline__ u16 f2bf(float f){
  unsigned x = __builtin_bit_cast(unsigned, f);
  unsigned r = x + 0x7fffu + ((x >> 16) & 1u);
  return (u16)(r >> 16);
}
__device__ __forceinline__ f32x4 mfma16(bf16x8 a, bf16x8 b, f32x4 c){
  return __builtin_amdgcn_mfma_f32_16x16x32_bf16(a, b, c, 0, 0, 0);
}
// swizzled LDS b128 fragment read
__device__ __forceinline__ bf16x8 ld512(const u16* buf, int row, int byte){
  return *(const bf16x8*)((const char*)buf + row*512 + (byte ^ ((row&7)<<4)));
}
__device__ __forceinline__ bf16x8 ld128(const u16* buf, int row, int byte){
  return *(const bf16x8*)((const char*)buf + row*128 + (byte ^ ((row&7)<<4)));
}

// ---------------- dtype detector (validated R3) ----------------
__global__ __launch_bounds__(64) void k_detect(const u16* __restrict__ x, int* __restrict__ flag){
  int lane = threadIdx.x;
  float mx = 0.f;
  for (int i = lane; i < 2048; i += 64){
    float v = fabsf(bf2f(x[i]));
    mx = (v < 64.0f) ? fmaxf(mx, v) : 1e30f;
  }
  #pragma unroll
  for (int d = 32; d; d >>= 1) mx = fmaxf(mx, __shfl_xor(mx, d));
  if (lane == 0) *flag = (mx < 64.0f) ? 1 : 0;
}

__global__ __launch_bounds__(256) void k_cast(const void* __restrict__ src, u16* __restrict__ dst,
                                              int n4, const int* __restrict__ flag){
  int i = blockIdx.x * 256 + threadIdx.x;
  if (i >= n4) return;
  if (*flag){
    *(u64*)(dst + (size_t)i*4) = *(const u64*)((const u16*)src + (size_t)i*4);
  } else {
    float4 v = *(const float4*)((const float*)src + (size_t)i*4);
    u64 pk = (u64)f2bf(v.x) | ((u64)f2bf(v.y)<<16) | ((u64)f2bf(v.z)<<32) | ((u64)f2bf(v.w)<<48);
    *(u64*)(dst + (size_t)i*4) = pk;
  }
}

__global__ __launch_bounds__(256) void k_wprep(const void* __restrict__ qw, const void* __restrict__ kw,
                                               float* __restrict__ qwf, float* __restrict__ kwf,
                                               const int* __restrict__ flag){
  int i = threadIdx.x;
  int f = *flag;
  qwf[i] = f ? bf2f(((const u16*)qw)[i]) : ((const float*)qw)[i];
  kwf[i] = f ? bf2f(((const u16*)kw)[i]) : ((const float*)kw)[i];
}

// ---------------- rope table ----------------
__global__ __launch_bounds__(256) void k_tab(float* __restrict__ tab){
  int idx = blockIdx.x * 256 + threadIdx.x;
  int t = idx >> 7, i = idx & 127;
  float fr = exp2f((float)i * (-13.287712379549449f / 128.0f));  // 10000^(-2i/256)
  float th = (float)t * fr;
  tab[idx*2 + 0] = cosf(th);
  tab[idx*2 + 1] = sinf(th);
}

// ---------------- fused QKV GEMM ----------------
__global__ __launch_bounds__(256) void k_qkv(const u16* __restrict__ x, const u16* __restrict__ wq,
                                             const u16* __restrict__ wkv,
                                             u16* __restrict__ q_raw, u16* __restrict__ kv_raw){
  __shared__ __align__(16) u16 Ax[64*256];
  __shared__ __align__(16) u16 Bw[64*256];
  int m0 = blockIdx.x * 64, n0 = blockIdx.y * 64;
  int tid = threadIdx.x;
  const u16* wsrc = (n0 < 4096) ? (wq + (size_t)n0*256) : (wkv + (size_t)(n0-4096)*256);
  int sr = tid >> 5, sk = tid & 31;
  #pragma unroll
  for (int u=0;u<8;++u){
    int r = sr + u*8;
    uint4 a = *(const uint4*)((const char*)(x    + (size_t)(m0+r)*256) + sk*16);
    uint4 b = *(const uint4*)((const char*)(wsrc + (size_t)r*256)      + sk*16);
    *(uint4*)((char*)&Ax[0] + r*512 + ((sk*16) ^ ((r&7)<<4))) = a;
    *(uint4*)((char*)&Bw[0] + r*512 + ((sk*16) ^ ((r&7)<<4))) = b;
  }
  __syncthreads();
  int w = tid>>6, lane = tid&63, ml = lane&15, g = lane>>4;
  int mh = w & 1, nh = w >> 1;
  f32x4 acc[2][2];
  #pragma unroll
  for (int mr=0;mr<2;++mr)
    #pragma unroll
    for (int j=0;j<2;++j) acc[mr][j] = f32x4{0.f,0.f,0.f,0.f};
  #pragma unroll
  for (int kk=0; kk<8; ++kk){
    bf16x8 af[2], bf[2];
    #pragma unroll
    for (int mr=0;mr<2;++mr) af[mr] = ld512(Ax, mh*32 + mr*16 + ml, kk*64 + g*16);
    #pragma unroll
    for (int j=0;j<2;++j)    bf[j]  = ld512(Bw, nh*32 + j*16 + ml,  kk*64 + g*16);
    #pragma unroll
    for (int mr=0;mr<2;++mr)
      #pragma unroll
      for (int j=0;j<2;++j) acc[mr][j] = mfma16(af[mr], bf[j], acc[mr][j]);
  }
  #pragma unroll
  for (int mr=0;mr<2;++mr)
    #pragma unroll
    for (int j=0;j<2;++j)
      #pragma unroll
      for (int r=0;r<4;++r){
        int row = m0 + mh*32 + mr*16 + 4*g + r;
        int n   = n0 + nh*32 + j*16 + ml;
        float v = acc[mr][j][r];
        if (n < 4096) q_raw[(size_t)row*4096 + n] = f2bf(v);
        else          kv_raw[(size_t)row*512 + (n - 4096)] = f2bf(v);
      }
}

// ---------------- rope + rmsnorm -> bf16 ----------------
__device__ __forceinline__ void rope_norm_row(const u16* __restrict__ src, const float* __restrict__ tab,
                                              const float* __restrict__ wn, u16* __restrict__ dst, int lane){
  union { u64 q; u16 u[4]; } iv;
  iv.q = *(const u64*)(src + lane*4);
  float v0 = bf2f(iv.u[0]), v1 = bf2f(iv.u[1]), v2 = bf2f(iv.u[2]), v3 = bf2f(iv.u[3]);
  float4 tc = *(const float4*)(tab + lane*4);
  float r0 = v0*tc.x - v1*tc.y;
  float r1 = v0*tc.y + v1*tc.x;
  float r2 = v2*tc.z - v3*tc.w;
  float r3 = v2*tc.w + v3*tc.z;
  float ss = r0*r0 + r1*r1 + r2*r2 + r3*r3;
  #pragma unroll
  for (int d=32; d; d>>=1) ss += __shfl_xor(ss, d);
  float sc = rsqrtf(ss * (1.0f/256.0f) + 1.1920929e-07f);
  u64 pk =  (u64)f2bf(r0*sc*wn[lane*4+0])
         | ((u64)f2bf(r1*sc*wn[lane*4+1]) << 16)
         | ((u64)f2bf(r2*sc*wn[lane*4+2]) << 32)
         | ((u64)f2bf(r3*sc*wn[lane*4+3]) << 48);
  *(u64*)(dst + lane*4) = pk;
}

__global__ __launch_bounds__(256) void k_ropenorm(const u16* __restrict__ q_raw, const u16* __restrict__ kv_raw,
                                                  const float* __restrict__ tab, const float* __restrict__ qw,
                                                  const float* __restrict__ kw, u16* __restrict__ qn,
                                                  u16* __restrict__ kn){
  int row  = blockIdx.x * 4 + (threadIdx.x >> 6);
  int lane = threadIdx.x & 63;
  if (row < 16*2048){
    int h = row >> 11, t = row & 2047;
    rope_norm_row(q_raw + (size_t)t*4096 + h*256, tab + (size_t)t*256, qw,
                  qn + ((size_t)h*2048 + t)*256, lane);
  } else {
    int t = row - 16*2048;
    rope_norm_row(kv_raw + (size_t)t*512, tab + (size_t)t*256, kw, kn + (size_t)t*256, lane);
  }
}

// ---------------- V transpose: vt[d][t] = v[t][d] ----------------
__global__ __launch_bounds__(256) void k_vtrans(const u16* __restrict__ kv_raw, u16* __restrict__ vt){
  __shared__ u16 Ts[64][72];
  int t0 = blockIdx.x*64, d0 = blockIdx.y*64;
  int tid = threadIdx.x;
  int rr = tid >> 3, c8 = (tid & 7) * 8;
  #pragma unroll
  for (int u=0;u<2;++u){
    int r = rr + u*32;
    uint4 v = *(const uint4*)(kv_raw + (size_t)(t0+r)*512 + 256 + d0 + c8);
    #pragma unroll
    for (int i=0;i<8;++i) Ts[r][c8+i] = ((const u16*)&v)[i];
  }
  __syncthreads();
  #pragma unroll
  for (int u=0;u<2;++u){
    int d = rr + u*32;
    u16 tmp[8];
    #pragma unroll
    for (int i=0;i<8;++i) tmp[i] = Ts[c8+i][d];
    *(uint4*)(vt + (size_t)(d0+d)*2048 + t0 + c8) = *(uint4*)tmp;
  }
}

// ---------------- windowed flash attention (MQA), swapped operands ----------------
// grid 512 = 16 heads x 32 q-tiles(64). 4 waves; wave w owns q rows q0+w*16..+15.
__global__ __launch_bounds__(256) void k_attn(const u16* __restrict__ qn, const u16* __restrict__ kn,
                                              const u16* __restrict__ vt, u16* __restrict__ aout){
  __shared__ __align__(16) u16 Ks[64*256];    // K tile (also Q staging), 512B rows swizzled
  __shared__ __align__(16) u16 Vs[256*64];    // V^T tile, 128B rows swizzled
  __shared__ __align__(16) u16 Ps[4][16*64];  // per-wave P [q][k], 128B rows swizzled
  int h = blockIdx.x >> 5, qt = blockIdx.x & 31;
  int q0 = qt * 64;
  int tid = threadIdx.x, w = tid >> 6, lane = tid & 63, ml = lane & 15, g = lane >> 4;
  int s_lo = q0 - WIN; if (s_lo < 0) s_lo = 0;
  int ntile = (q0 + 64 - s_lo) >> 6;
  int sr = tid >> 5, sk = tid & 31;       // K/Q staging: rows 8u+sr, 32x16B slots
  int vd = tid >> 3, vs = tid & 7;        // V staging: rows 32u+vd, 8x16B slots

  // prefetch tile 0 K/V into regs
  uint4 kreg[8], vreg[8];
  #pragma unroll
  for (int u=0;u<8;++u){
    int r = sr + u*8;
    kreg[u] = *(const uint4*)((const char*)(kn + (size_t)(s_lo + r)*256) + sk*16);
    int d = vd + u*32;
    vreg[u] = *(const uint4*)((const char*)(vt + (size_t)d*2048 + s_lo) + vs*16);
  }
  // stage Q through Ks, pick up fragments
  {
    const u16* qsrc = qn + ((size_t)h*2048 + q0)*256;
    #pragma unroll
    for (int u=0;u<8;++u){
      int r = sr + u*8;
      uint4 qv = *(const uint4*)((const char*)(qsrc + (size_t)r*256) + sk*16);
      *(uint4*)((char*)&Ks[0] + r*512 + ((sk*16) ^ ((r&7)<<4))) = qv;
    }
  }
  __syncthreads();
  bf16x8 qf[8];
  #pragma unroll
  for (int kk=0; kk<8; ++kk) qf[kk] = ld512(Ks, w*16 + ml, kk*64 + g*16);

  float mx = -1e30f, ls = 0.f;
  f32x4 o[16];
  #pragma unroll
  for (int f=0; f<16; ++f) o[f] = f32x4{0.f,0.f,0.f,0.f};
  int tq = q0 + w*16 + ml;

  for (int kt=0; kt<ntile; ++kt){
    int s0 = s_lo + kt*64;
    __syncthreads();                       // previous tile's LDS reads done (incl. qf pickup)
    #pragma unroll
    for (int u=0;u<8;++u){
      int r = sr + u*8;
      *(uint4*)((char*)&Ks[0] + r*512 + ((sk*16) ^ ((r&7)<<4))) = kreg[u];
      int d = vd + u*32;
      *(uint4*)((char*)&Vs[0] + d*128 + ((vs*16) ^ ((d&7)<<4))) = vreg[u];
    }
    __syncthreads();
    if (kt+1 < ntile){                     // T14: issue next-tile loads before compute
      int s1 = s0 + 64;
      #pragma unroll
      for (int u=0;u<8;++u){
        int r = sr + u*8;
        kreg[u] = *(const uint4*)((const char*)(kn + (size_t)(s1 + r)*256) + sk*16);
        int d = vd + u*32;
        vreg[u] = *(const uint4*)((const char*)(vt + (size_t)d*2048 + s1) + vs*16);
      }
    }
    // S^T = K @ Q: C col(ml) = q, row(4g+r) = key
    f32x4 s[4];
    #pragma unroll
    for (int j=0;j<4;++j) s[j] = f32x4{0.f,0.f,0.f,0.f};
    #pragma unroll
    for (int kk=0; kk<8; ++kk)
      #pragma unroll
      for (int j=0;j<4;++j){
        bf16x8 kf = ld512(Ks, j*16 + ml, kk*64 + g*16);
        s[j] = mfma16(kf, qf[kk], s[j]);
      }
    // mask + scale + row max
    float best = -1e30f;
    #pragma unroll
    for (int j=0;j<4;++j)
      #pragma unroll
      for (int r=0;r<4;++r){
        int key = s0 + j*16 + 4*g + r;
        float v = s[j][r] * 0.0625f;
        bool ok = (key <= tq) && (tq - key <= WIN);
        v = ok ? v : -1e30f;
        s[j][r] = v;
        best = fmaxf(best, v);
      }
    best = fmaxf(best, __shfl_xor(best, 16));
    best = fmaxf(best, __shfl_xor(best, 32));
    // T13 defer-max
    if (__ballot(best > mx + 8.f)){
      float mn = fmaxf(mx, best);
      float corr = __expf(mx - mn);
      mx = mn; ls *= corr;
      #pragma unroll
      for (int f=0; f<16; ++f) o[f] *= corr;
    }
    // P = exp(S - mx): pack 4 contiguous keys -> u64 LDS write
    float rs = 0.f;
    #pragma unroll
    for (int j=0;j<4;++j){
      u64 pk = 0;
      #pragma unroll
      for (int r=0;r<4;++r){
        float p = __expf(s[j][r] - mx);
        rs += p;
        pk |= (u64)f2bf(p) << (16*r);
      }
      *(u64*)((char*)&Ps[w][0] + ml*128 + ((32*j + 8*g) ^ ((ml&7)<<4))) = pk;
    }
    rs += __shfl_xor(rs, 16);
    rs += __shfl_xor(rs, 32);
    ls += rs;
    // O^T += V^T @ P
    #pragma unroll
    for (int kk2=0; kk2<2; ++kk2){
      bf16x8 pb = ld128(&Ps[w][0], ml, kk2*64 + g*16);
      #pragma unroll
      for (int f=0; f<16; ++f){
        bf16x8 vf = ld128(Vs, f*16 + ml, kk2*64 + g*16);
        o[f] = mfma16(vf, pb, o[f]);
      }
    }
  }
  // epilogue: element (d=f*16+4g+r, q=tq); 4 d's pack to u64
  float inv = 1.0f / ls;
  u16* dst = aout + ((size_t)h*2048 + tq)*256;
  #pragma unroll
  for (int f=0; f<16; ++f){
    f32x4 v = o[f];
    u64 pk = (u64)f2bf(v[0]*inv) | ((u64)f2bf(v[1]*inv)<<16)
           | ((u64)f2bf(v[2]*inv)<<32) | ((u64)f2bf(v[3]*inv)<<48);
    *(u64*)(dst + f*16 + 4*g) = pk;
  }
}

// ---------------- out projection, split-K x4 -> f32 partials ----------------
__global__ __launch_bounds__(256) void k_oproj(const u16* __restrict__ aout, const u16* __restrict__ wo,
                                               float* __restrict__ pout){
  __shared__ __align__(16) u16 As[64*256];
  __shared__ __align__(16) u16 Bs[64*256];
  int t0 = blockIdx.x * 64, c0 = blockIdx.y * 64, ksp = blockIdx.z;
  int tid = threadIdx.x, w = tid>>6, lane = tid&63, ml = lane&15, g = lane>>4;
  int mh = w & 1, nh = w >> 1;
  int sr = tid >> 5, sk = tid & 31;
  f32x4 acc[2][2];
  #pragma unroll
  for (int mr=0;mr<2;++mr)
    #pragma unroll
    for (int j=0;j<2;++j) acc[mr][j] = f32x4{0.f,0.f,0.f,0.f};
  for (int kc = ksp*4; kc < ksp*4 + 4; ++kc){
    __syncthreads();
    #pragma unroll
    for (int u=0;u<8;++u){
      int r = sr + u*8;
      uint4 a = *(const uint4*)((const char*)(aout + ((size_t)kc*2048 + t0 + r)*256) + sk*16);
      uint4 b = *(const uint4*)((const char*)(wo + (size_t)(c0+r)*4096 + kc*256) + sk*16);
      *(uint4*)((char*)&As[0] + r*512 + ((sk*16) ^ ((r&7)<<4))) = a;
      *(uint4*)((char*)&Bs[0] + r*512 + ((sk*16) ^ ((r&7)<<4))) = b;
    }
    __syncthreads();
    #pragma unroll
    for (int kk=0; kk<8; ++kk){
      bf16x8 af[2], bf[2];
      #pragma unroll
      for (int mr=0;mr<2;++mr) af[mr] = ld512(As, mh*32 + mr*16 + ml, kk*64 + g*16);
      #pragma unroll
      for (int j=0;j<2;++j)    bf[j]  = ld512(Bs, nh*32 + j*16 + ml,  kk*64 + g*16);
      #pragma unroll
      for (int mr=0;mr<2;++mr)
        #pragma unroll
        for (int j=0;j<2;++j) acc[mr][j] = mfma16(af[mr], bf[j], acc[mr][j]);
    }
  }
  #pragma unroll
  for (int mr=0;mr<2;++mr)
    #pragma unroll
    for (int j=0;j<2;++j)
      #pragma unroll
      for (int r=0;r<4;++r){
        int t = t0 + mh*32 + mr*16 + 4*g + r;
        int c = c0 + nh*32 + j*16 + ml;
        pout[((size_t)ksp*2048 + t)*256 + c] = acc[mr][j][r];
      }
}

__global__ __launch_bounds__(256) void k_red(const float* __restrict__ pout, void* __restrict__ out,
                                             const int* __restrict__ flag){
  int i = blockIdx.x * 256 + threadIdx.x;
  float v = pout[i] + pout[i + 2048*256] + pout[i + 2*2048*256] + pout[i + 3*2048*256];
  if (*flag) ((u16*)out)[i] = f2bf(v);
  else       ((float*)out)[i] = v;
}

extern "C" void kernel_launch(void* const* d_in, const int* in_sizes, int n_in,
                              void* d_out, int out_size, void* d_ws, size_t ws_size,
                              hipStream_t stream) {
  (void)in_sizes; (void)n_in; (void)out_size; (void)ws_size;
  const void* x_r   = d_in[0];
  const void* wq_r  = d_in[1];
  const void* wkv_r = d_in[2];
  const void* wo_r  = d_in[3];
  const void* qw_r  = d_in[4];
  const void* kw_r  = d_in[5];
  char* ws = (char*)d_ws;
  const size_t MB = 1048576;
  u16*   xb     = (u16*)  (ws);                 // [0, 1)
  u16*   wqb    = (u16*)  (ws + 1*MB);          // [1, 3)
  u16*   wkvb   = (u16*)  (ws + 3*MB);          // [3, 3.5)
  u16*   wob    = (u16*)  (ws + 3*MB + MB/2);   // [3.5, 5.5)
  float* tab    = (float*)(ws + 5*MB + MB/2);   // [5.5, 7.5)
  u16*   q_raw  = (u16*)  (ws + 7*MB + MB/2);   // [7.5, 23.5)
  u16*   aout   = q_raw;                        // alias: q_raw dead after k_ropenorm
  u16*   kv_raw = (u16*)  (ws + 23*MB + MB/2);  // [23.5, 25.5)
  u16*   qn     = (u16*)  (ws + 25*MB + MB/2);  // [25.5, 41.5)
  float* pout   = (float*)qn;                   // alias: qn dead after k_attn (8 MB)
  u16*   kn     = (u16*)  (ws + 41*MB + MB/2);  // [41.5, 42.5)
  u16*   vt     = (u16*)  (ws + 42*MB + MB/2);  // [42.5, 43.5)
  int*   flag   = (int*)  (ws + 43*MB + MB/2);
  float* qwf    = (float*)(ws + 43*MB + MB/2 + 256);
  float* kwf    = (float*)(ws + 43*MB + MB/2 + 1280);

  k_detect<<<dim3(1),   dim3(64),  0, stream>>>((const u16*)x_r, flag);
  k_cast  <<<dim3(512), dim3(256), 0, stream>>>(x_r,   xb,   2048*256/4, flag);
  k_cast  <<<dim3(1024),dim3(256), 0, stream>>>(wq_r,  wqb,  4096*256/4, flag);
  k_cast  <<<dim3(128), dim3(256), 0, stream>>>(wkv_r, wkvb, 512*256/4,  flag);
  k_cast  <<<dim3(1024),dim3(256), 0, stream>>>(wo_r,  wob,  256*4096/4, flag);
  k_wprep <<<dim3(1),   dim3(256), 0, stream>>>(qw_r, kw_r, qwf, kwf, flag);
  k_tab   <<<dim3(1024),dim3(256), 0, stream>>>(tab);
  k_qkv     <<<dim3(32, 72),   dim3(256), 0, stream>>>(xb, wqb, wkvb, q_raw, kv_raw);
  k_ropenorm<<<dim3(8704),     dim3(256), 0, stream>>>(q_raw, kv_raw, tab, qwf, kwf, qn, kn);
  k_vtrans  <<<dim3(32, 4),    dim3(256), 0, stream>>>(kv_raw, vt);
  k_attn    <<<dim3(512),      dim3(256), 0, stream>>>(qn, kn, vt, aout);
  k_oproj   <<<dim3(32, 4, 4), dim3(256), 0, stream>>>(aout, wob, pout);
  k_red     <<<dim3(2048),     dim3(256), 0, stream>>>(pout, d_out, flag);
}

// Round 6
// 108.795 us; speedup vs baseline: 1.6739x; 1.6739x over previous
//
#include <hip/hip_runtime.h>

#define TT   2048
#define WIN  512

typedef unsigned short u16;
typedef unsigned long long u64;
typedef __bf16 bf16x8 __attribute__((ext_vector_type(8)));
typedef float  f32x4  __attribute__((ext_vector_type(4)));

__device__ __forceinline__ float bf2f(u16 u){
  unsigned v = ((unsigned)u) << 16;
  return __builtin_bit_cast(float, v);
}
__device__ __forceinline__ u16 f2bf(float f){
  unsigned x = __builtin_bit_cast(unsigned, f);
  unsigned r = x + 0x7fffu + ((x >> 16) & 1u);
  return (u16)(r >> 16);
}
__device__ __forceinline__ f32x4 mfma16(bf16x8 a, bf16x8 b, f32x4 c){
  return __builtin_amdgcn_mfma_f32_16x16x32_bf16(a, b, c, 0, 0, 0);
}
// swizzled LDS b128 fragment read
__device__ __forceinline__ bf16x8 ld512(const u16* buf, int row, int byte){
  return *(const bf16x8*)((const char*)buf + row*512 + (byte ^ ((row&7)<<4)));
}
__device__ __forceinline__ bf16x8 ld128(const u16* buf, int row, int byte){
  return *(const bf16x8*)((const char*)buf + row*128 + (byte ^ ((row&7)<<4)));
}
// async global->LDS, 16B per lane; LDS dest = wave-uniform base + lane*16
#define GL16(gp, lp) __builtin_amdgcn_global_load_lds( \
    (const __attribute__((address_space(1))) unsigned int*)(gp), \
    (__attribute__((address_space(3))) unsigned int*)(lp), 16, 0, 0)

// ---------------- dtype detector (validated R3) ----------------
__global__ __launch_bounds__(64) void k_detect(const u16* __restrict__ x, int* __restrict__ flag){
  int lane = threadIdx.x;
  float mx = 0.f;
  for (int i = lane; i < 2048; i += 64){
    float v = fabsf(bf2f(x[i]));
    mx = (v < 64.0f) ? fmaxf(mx, v) : 1e30f;
  }
  #pragma unroll
  for (int d = 32; d; d >>= 1) mx = fmaxf(mx, __shfl_xor(mx, d));
  if (lane == 0) *flag = (mx < 64.0f) ? 1 : 0;
}

__global__ __launch_bounds__(256) void k_cast(const void* __restrict__ src, u16* __restrict__ dst,
                                              int n4, const int* __restrict__ flag){
  int i = blockIdx.x * 256 + threadIdx.x;
  if (i >= n4) return;
  if (*flag){
    *(u64*)(dst + (size_t)i*4) = *(const u64*)((const u16*)src + (size_t)i*4);
  } else {
    float4 v = *(const float4*)((const float*)src + (size_t)i*4);
    u64 pk = (u64)f2bf(v.x) | ((u64)f2bf(v.y)<<16) | ((u64)f2bf(v.z)<<32) | ((u64)f2bf(v.w)<<48);
    *(u64*)(dst + (size_t)i*4) = pk;
  }
}

__global__ __launch_bounds__(256) void k_wprep(const void* __restrict__ qw, const void* __restrict__ kw,
                                               float* __restrict__ qwf, float* __restrict__ kwf,
                                               const int* __restrict__ flag){
  int i = threadIdx.x;
  int f = *flag;
  qwf[i] = f ? bf2f(((const u16*)qw)[i]) : ((const float*)qw)[i];
  kwf[i] = f ? bf2f(((const u16*)kw)[i]) : ((const float*)kw)[i];
}

// ---------------- rope table ----------------
__global__ __launch_bounds__(256) void k_tab(float* __restrict__ tab){
  int idx = blockIdx.x * 256 + threadIdx.x;
  int t = idx >> 7, i = idx & 127;
  float fr = exp2f((float)i * (-13.287712379549449f / 128.0f));  // 10000^(-2i/256)
  float th = (float)t * fr;
  tab[idx*2 + 0] = cosf(th);
  tab[idx*2 + 1] = sinf(th);
}

// ---------------- fused QKV GEMM ----------------
__global__ __launch_bounds__(256) void k_qkv(const u16* __restrict__ x, const u16* __restrict__ wq,
                                             const u16* __restrict__ wkv,
                                             u16* __restrict__ q_raw, u16* __restrict__ kv_raw){
  __shared__ __align__(16) u16 Ax[64*256];
  __shared__ __align__(16) u16 Bw[64*256];
  int m0 = blockIdx.x * 64, n0 = blockIdx.y * 64;
  int tid = threadIdx.x;
  const u16* wsrc = (n0 < 4096) ? (wq + (size_t)n0*256) : (wkv + (size_t)(n0-4096)*256);
  int sr = tid >> 5, sk = tid & 31;
  #pragma unroll
  for (int u=0;u<8;++u){
    int r = sr + u*8;
    uint4 a = *(const uint4*)((const char*)(x    + (size_t)(m0+r)*256) + sk*16);
    uint4 b = *(const uint4*)((const char*)(wsrc + (size_t)r*256)      + sk*16);
    *(uint4*)((char*)&Ax[0] + r*512 + ((sk*16) ^ ((r&7)<<4))) = a;
    *(uint4*)((char*)&Bw[0] + r*512 + ((sk*16) ^ ((r&7)<<4))) = b;
  }
  __syncthreads();
  int w = tid>>6, lane = tid&63, ml = lane&15, g = lane>>4;
  int mh = w & 1, nh = w >> 1;
  f32x4 acc[2][2];
  #pragma unroll
  for (int mr=0;mr<2;++mr)
    #pragma unroll
    for (int j=0;j<2;++j) acc[mr][j] = f32x4{0.f,0.f,0.f,0.f};
  #pragma unroll
  for (int kk=0; kk<8; ++kk){
    bf16x8 af[2], bf[2];
    #pragma unroll
    for (int mr=0;mr<2;++mr) af[mr] = ld512(Ax, mh*32 + mr*16 + ml, kk*64 + g*16);
    #pragma unroll
    for (int j=0;j<2;++j)    bf[j]  = ld512(Bw, nh*32 + j*16 + ml,  kk*64 + g*16);
    #pragma unroll
    for (int mr=0;mr<2;++mr)
      #pragma unroll
      for (int j=0;j<2;++j) acc[mr][j] = mfma16(af[mr], bf[j], acc[mr][j]);
  }
  #pragma unroll
  for (int mr=0;mr<2;++mr)
    #pragma unroll
    for (int j=0;j<2;++j)
      #pragma unroll
      for (int r=0;r<4;++r){
        int row = m0 + mh*32 + mr*16 + 4*g + r;
        int n   = n0 + nh*32 + j*16 + ml;
        float v = acc[mr][j][r];
        if (n < 4096) q_raw[(size_t)row*4096 + n] = f2bf(v);
        else          kv_raw[(size_t)row*512 + (n - 4096)] = f2bf(v);
      }
}

// ---------------- rope + rmsnorm -> bf16 (q pre-scaled by 1/16) ----------------
__device__ __forceinline__ void rope_norm_row(const u16* __restrict__ src, const float* __restrict__ tab,
                                              const float* __restrict__ wn, u16* __restrict__ dst,
                                              int lane, float post){
  union { u64 q; u16 u[4]; } iv;
  iv.q = *(const u64*)(src + lane*4);
  float v0 = bf2f(iv.u[0]), v1 = bf2f(iv.u[1]), v2 = bf2f(iv.u[2]), v3 = bf2f(iv.u[3]);
  float4 tc = *(const float4*)(tab + lane*4);
  float r0 = v0*tc.x - v1*tc.y;
  float r1 = v0*tc.y + v1*tc.x;
  float r2 = v2*tc.z - v3*tc.w;
  float r3 = v2*tc.w + v3*tc.z;
  float ss = r0*r0 + r1*r1 + r2*r2 + r3*r3;
  #pragma unroll
  for (int d=32; d; d>>=1) ss += __shfl_xor(ss, d);
  float sc = rsqrtf(ss * (1.0f/256.0f) + 1.1920929e-07f) * post;
  u64 pk =  (u64)f2bf(r0*sc*wn[lane*4+0])
         | ((u64)f2bf(r1*sc*wn[lane*4+1]) << 16)
         | ((u64)f2bf(r2*sc*wn[lane*4+2]) << 32)
         | ((u64)f2bf(r3*sc*wn[lane*4+3]) << 48);
  *(u64*)(dst + lane*4) = pk;
}

__global__ __launch_bounds__(256) void k_ropenorm(const u16* __restrict__ q_raw, const u16* __restrict__ kv_raw,
                                                  const float* __restrict__ tab, const float* __restrict__ qw,
                                                  const float* __restrict__ kw, u16* __restrict__ qn,
                                                  u16* __restrict__ kn){
  int row  = blockIdx.x * 4 + (threadIdx.x >> 6);
  int lane = threadIdx.x & 63;
  if (row < 16*2048){
    int h = row >> 11, t = row & 2047;
    rope_norm_row(q_raw + (size_t)t*4096 + h*256, tab + (size_t)t*256, qw,
                  qn + ((size_t)h*2048 + t)*256, lane, 0.0625f);   // fold 1/sqrt(256)
  } else {
    int t = row - 16*2048;
    rope_norm_row(kv_raw + (size_t)t*512, tab + (size_t)t*256, kw, kn + (size_t)t*256, lane, 1.0f);
  }
}

// ---------------- V transpose: vt[d][t] = v[t][d] ----------------
__global__ __launch_bounds__(256) void k_vtrans(const u16* __restrict__ kv_raw, u16* __restrict__ vt){
  __shared__ u16 Ts[64][72];
  int t0 = blockIdx.x*64, d0 = blockIdx.y*64;
  int tid = threadIdx.x;
  int rr = tid >> 3, c8 = (tid & 7) * 8;
  #pragma unroll
  for (int u=0;u<2;++u){
    int r = rr + u*32;
    uint4 v = *(const uint4*)(kv_raw + (size_t)(t0+r)*512 + 256 + d0 + c8);
    #pragma unroll
    for (int i=0;i<8;++i) Ts[r][c8+i] = ((const u16*)&v)[i];
  }
  __syncthreads();
  #pragma unroll
  for (int u=0;u<2;++u){
    int d = rr + u*32;
    u16 tmp[8];
    #pragma unroll
    for (int i=0;i<8;++i) tmp[i] = Ts[c8+i][d];
    *(uint4*)(vt + (size_t)(d0+d)*2048 + t0 + c8) = *(uint4*)tmp;
  }
}

// ---------------- windowed flash attention (MQA) ----------------
// grid 256 = 16 heads x 16 q-tiles(128 rows). 8 waves; wave w owns rows Q0+w*16..+15.
// K/V double-buffered in LDS via global_load_lds (pre-swizzled source), counted vmcnt.
__global__ __launch_bounds__(512, 2) void k_attn(const u16* __restrict__ qn, const u16* __restrict__ kn,
                                                 const u16* __restrict__ vt, u16* __restrict__ aout){
  __shared__ __align__(16) u16 Ks[2][64*256];  // K tile dbuf (also Q staging), 512B rows swz
  __shared__ __align__(16) u16 Vs[2][256*64];  // V^T tile dbuf, 128B rows swz
  __shared__ __align__(16) u16 Ps[8][16*64];   // per-wave P [q][k], 128B rows swz
  int h = blockIdx.x >> 4, qt = blockIdx.x & 15;
  int Q0 = qt * 128;
  int tid = threadIdx.x, w = tid >> 6, lane = tid & 63, ml = lane & 15, g = lane >> 4;
  int s_lo = Q0 - WIN; if (s_lo < 0) s_lo = 0;
  int ntile = (Q0 + 128 - s_lo) >> 6;

  // ---- stage Q (128 rows) into Ks[0..1], read fragments, then free the buffers ----
  {
    int sr = tid >> 5, sk = tid & 31;
    const u16* qsrc = qn + ((size_t)h*2048 + Q0)*256;
    #pragma unroll
    for (int u=0;u<8;++u){
      int row = sr + u*16;                  // 0..127
      uint4 qv = *(const uint4*)((const char*)(qsrc + (size_t)row*256) + sk*16);
      int lr = row & 63;
      *(uint4*)((char*)&Ks[row>>6][0] + lr*512 + ((sk*16) ^ ((lr&7)<<4))) = qv;
    }
  }
  __syncthreads();
  bf16x8 qf[8];
  #pragma unroll
  for (int kk=0; kk<8; ++kk) qf[kk] = ld512(&Ks[w>>2][0], (w&3)*16 + ml, kk*64 + g*16);
  __syncthreads();   // all Q reads done; Ks free for K staging

  // staging geometry (per wave: 4 K-gloads 2 rows each, 4 V-gloads 8 rows each)
  int krow = w*8 + (lane>>5), kslot = lane & 31;
  int vrow = w*32 + (lane>>3), vslot = lane & 7;

  // issue tile 0
  {
    int s0 = s_lo;
    #pragma unroll
    for (int i=0;i<4;++i){
      int r = krow + i*2;
      GL16(kn + (size_t)(s0 + r)*256 + ((kslot ^ (r&7))*8), &Ks[0][(w*8 + i*2)*256]);
    }
    #pragma unroll
    for (int i=0;i<4;++i){
      int d = vrow + i*8;
      GL16(vt + (size_t)d*2048 + s0 + ((vslot ^ (d&7))*8), &Vs[0][(w*32 + i*8)*64]);
    }
  }

  float mx = -1e30f, ls = 0.f;
  f32x4 o[16];
  #pragma unroll
  for (int f=0; f<16; ++f) o[f] = f32x4{0.f,0.f,0.f,0.f};
  int tq = Q0 + w*16 + ml;
  int wmin = Q0 + w*16, wmax = wmin + 15;
  int cur = 0;

  for (int kt=0; kt<ntile; ++kt){
    int s0 = s_lo + kt*64;
    bool haveNext = (kt+1 < ntile);
    if (haveNext){
      int s1 = s0 + 64;
      #pragma unroll
      for (int i=0;i<4;++i){
        int r = krow + i*2;
        GL16(kn + (size_t)(s1 + r)*256 + ((kslot ^ (r&7))*8), &Ks[cur^1][(w*8 + i*2)*256]);
      }
      #pragma unroll
      for (int i=0;i<4;++i){
        int d = vrow + i*8;
        GL16(vt + (size_t)d*2048 + s1 + ((vslot ^ (d&7))*8), &Vs[cur^1][(w*32 + i*8)*64]);
      }
      asm volatile("s_waitcnt vmcnt(8)" ::: "memory");   // current tile's 8 arrived
    } else {
      asm volatile("s_waitcnt vmcnt(0)" ::: "memory");
    }
    __builtin_amdgcn_s_barrier();
    __builtin_amdgcn_sched_barrier(0);

    bool act = (s0 <= wmax) && (s0 + 63 + WIN >= wmin);
    if (act){
      const u16* kb = &Ks[cur][0];
      const u16* vb = &Vs[cur][0];
      // S^T = K @ Q : C col(ml)=q, row(4g+r)=key
      f32x4 s[4];
      #pragma unroll
      for (int j=0;j<4;++j) s[j] = f32x4{0.f,0.f,0.f,0.f};
      __builtin_amdgcn_s_setprio(1);
      #pragma unroll
      for (int kk=0; kk<8; ++kk)
        #pragma unroll
        for (int j=0;j<4;++j)
          s[j] = mfma16(ld512(kb, j*16 + ml, kk*64 + g*16), qf[kk], s[j]);
      __builtin_amdgcn_s_setprio(0);
      // mask + row max
      float best = -1e30f;
      #pragma unroll
      for (int j=0;j<4;++j)
        #pragma unroll
        for (int r=0;r<4;++r){
          int key = s0 + j*16 + 4*g + r;
          float v = s[j][r];
          bool ok = (key <= tq) && (tq - key <= WIN);
          v = ok ? v : -1e30f;
          s[j][r] = v;
          best = fmaxf(best, v);
        }
      best = fmaxf(best, __shfl_xor(best, 16));
      best = fmaxf(best, __shfl_xor(best, 32));
      // T13 defer-max
      if (__ballot(best > mx + 8.f)){
        float mn = fmaxf(mx, best);
        float corr = __expf(mx - mn);
        mx = mn; ls *= corr;
        #pragma unroll
        for (int f=0; f<16; ++f) o[f] *= corr;
      }
      // P = exp(S - mx) with fully-masked guard; pack 4 keys -> u64 LDS write
      float rs = 0.f;
      #pragma unroll
      for (int j=0;j<4;++j){
        u64 pk = 0;
        #pragma unroll
        for (int r=0;r<4;++r){
          float v = s[j][r];
          float p = (v <= -1e29f) ? 0.f : __expf(v - mx);
          rs += p;
          pk |= (u64)f2bf(p) << (16*r);
        }
        *(u64*)((char*)&Ps[w][0] + ml*128 + ((32*j + 8*g) ^ ((ml&7)<<4))) = pk;
      }
      rs += __shfl_xor(rs, 16);
      rs += __shfl_xor(rs, 32);
      ls += rs;
      // O^T += V^T @ P
      __builtin_amdgcn_s_setprio(1);
      #pragma unroll
      for (int kk2=0; kk2<2; ++kk2){
        bf16x8 pb = ld128(&Ps[w][0], ml, kk2*64 + g*16);
        #pragma unroll
        for (int f=0; f<16; ++f){
          bf16x8 vf = ld128(vb, f*16 + ml, kk2*64 + g*16);
          o[f] = mfma16(vf, pb, o[f]);
        }
      }
      __builtin_amdgcn_s_setprio(0);
    }
    __builtin_amdgcn_s_barrier();
    __builtin_amdgcn_sched_barrier(0);
    cur ^= 1;
  }
  // epilogue: element (d=f*16+4g+r, q=tq); 4 d's pack to u64
  float inv = 1.0f / ls;
  u16* dst = aout + ((size_t)h*2048 + tq)*256;
  #pragma unroll
  for (int f=0; f<16; ++f){
    f32x4 v = o[f];
    u64 pk = (u64)f2bf(v[0]*inv) | ((u64)f2bf(v[1]*inv)<<16)
           | ((u64)f2bf(v[2]*inv)<<32) | ((u64)f2bf(v[3]*inv)<<48);
    *(u64*)(dst + f*16 + 4*g) = pk;
  }
}

// ---------------- out projection, split-K x4 -> f32 partials ----------------
__global__ __launch_bounds__(256) void k_oproj(const u16* __restrict__ aout, const u16* __restrict__ wo,
                                               float* __restrict__ pout){
  __shared__ __align__(16) u16 As[64*256];
  __shared__ __align__(16) u16 Bs[64*256];
  int t0 = blockIdx.x * 64, c0 = blockIdx.y * 64, ksp = blockIdx.z;
  int tid = threadIdx.x, w = tid>>6, lane = tid&63, ml = lane&15, g = lane>>4;
  int mh = w & 1, nh = w >> 1;
  int sr = tid >> 5, sk = tid & 31;
  f32x4 acc[2][2];
  #pragma unroll
  for (int mr=0;mr<2;++mr)
    #pragma unroll
    for (int j=0;j<2;++j) acc[mr][j] = f32x4{0.f,0.f,0.f,0.f};
  for (int kc = ksp*4; kc < ksp*4 + 4; ++kc){
    __syncthreads();
    #pragma unroll
    for (int u=0;u<8;++u){
      int r = sr + u*8;
      uint4 a = *(const uint4*)((const char*)(aout + ((size_t)kc*2048 + t0 + r)*256) + sk*16);
      uint4 b = *(const uint4*)((const char*)(wo + (size_t)(c0+r)*4096 + kc*256) + sk*16);
      *(uint4*)((char*)&As[0] + r*512 + ((sk*16) ^ ((r&7)<<4))) = a;
      *(uint4*)((char*)&Bs[0] + r*512 + ((sk*16) ^ ((r&7)<<4))) = b;
    }
    __syncthreads();
    #pragma unroll
    for (int kk=0; kk<8; ++kk){
      bf16x8 af[2], bf[2];
      #pragma unroll
      for (int mr=0;mr<2;++mr) af[mr] = ld512(As, mh*32 + mr*16 + ml, kk*64 + g*16);
      #pragma unroll
      for (int j=0;j<2;++j)    bf[j]  = ld512(Bs, nh*32 + j*16 + ml,  kk*64 + g*16);
      #pragma unroll
      for (int mr=0;mr<2;++mr)
        #pragma unroll
        for (int j=0;j<2;++j) acc[mr][j] = mfma16(af[mr], bf[j], acc[mr][j]);
    }
  }
  #pragma unroll
  for (int mr=0;mr<2;++mr)
    #pragma unroll
    for (int j=0;j<2;++j)
      #pragma unroll
      for (int r=0;r<4;++r){
        int t = t0 + mh*32 + mr*16 + 4*g + r;
        int c = c0 + nh*32 + j*16 + ml;
        pout[((size_t)ksp*2048 + t)*256 + c] = acc[mr][j][r];
      }
}

__global__ __launch_bounds__(256) void k_red(const float* __restrict__ pout, void* __restrict__ out,
                                             const int* __restrict__ flag){
  int i = blockIdx.x * 256 + threadIdx.x;
  float v = pout[i] + pout[i + 2048*256] + pout[i + 2*2048*256] + pout[i + 3*2048*256];
  if (*flag) ((u16*)out)[i] = f2bf(v);
  else       ((float*)out)[i] = v;
}

extern "C" void kernel_launch(void* const* d_in, const int* in_sizes, int n_in,
                              void* d_out, int out_size, void* d_ws, size_t ws_size,
                              hipStream_t stream) {
  (void)in_sizes; (void)n_in; (void)out_size; (void)ws_size;
  const void* x_r   = d_in[0];
  const void* wq_r  = d_in[1];
  const void* wkv_r = d_in[2];
  const void* wo_r  = d_in[3];
  const void* qw_r  = d_in[4];
  const void* kw_r  = d_in[5];
  char* ws = (char*)d_ws;
  const size_t MB = 1048576;
  u16*   xb     = (u16*)  (ws);                 // [0, 1)
  u16*   wqb    = (u16*)  (ws + 1*MB);          // [1, 3)
  u16*   wkvb   = (u16*)  (ws + 3*MB);          // [3, 3.5)
  u16*   wob    = (u16*)  (ws + 3*MB + MB/2);   // [3.5, 5.5)
  float* tab    = (float*)(ws + 5*MB + MB/2);   // [5.5, 7.5)
  u16*   q_raw  = (u16*)  (ws + 7*MB + MB/2);   // [7.5, 23.5)
  u16*   aout   = q_raw;                        // alias: q_raw dead after k_ropenorm
  u16*   kv_raw = (u16*)  (ws + 23*MB + MB/2);  // [23.5, 25.5)
  u16*   qn     = (u16*)  (ws + 25*MB + MB/2);  // [25.5, 41.5)
  float* pout   = (float*)qn;                   // alias: qn dead after k_attn (8 MB)
  u16*   kn     = (u16*)  (ws + 41*MB + MB/2);  // [41.5, 42.5)
  u16*   vt     = (u16*)  (ws + 42*MB + MB/2);  // [42.5, 43.5)
  int*   flag   = (int*)  (ws + 43*MB + MB/2);
  float* qwf    = (float*)(ws + 43*MB + MB/2 + 256);
  float* kwf    = (float*)(ws + 43*MB + MB/2 + 1280);

  k_detect<<<dim3(1),   dim3(64),  0, stream>>>((const u16*)x_r, flag);
  k_cast  <<<dim3(512), dim3(256), 0, stream>>>(x_r,   xb,   2048*256/4, flag);
  k_cast  <<<dim3(1024),dim3(256), 0, stream>>>(wq_r,  wqb,  4096*256/4, flag);
  k_cast  <<<dim3(128), dim3(256), 0, stream>>>(wkv_r, wkvb, 512*256/4,  flag);
  k_cast  <<<dim3(1024),dim3(256), 0, stream>>>(wo_r,  wob,  256*4096/4, flag);
  k_wprep <<<dim3(1),   dim3(256), 0, stream>>>(qw_r, kw_r, qwf, kwf, flag);
  k_tab   <<<dim3(1024),dim3(256), 0, stream>>>(tab);
  k_qkv     <<<dim3(32, 72),   dim3(256), 0, stream>>>(xb, wqb, wkvb, q_raw, kv_raw);
  k_ropenorm<<<dim3(8704),     dim3(256), 0, stream>>>(q_raw, kv_raw, tab, qwf, kwf, qn, kn);
  k_vtrans  <<<dim3(32, 4),    dim3(256), 0, stream>>>(kv_raw, vt);
  k_attn    <<<dim3(256),      dim3(512), 0, stream>>>(qn, kn, vt, aout);
  k_oproj   <<<dim3(32, 4, 4), dim3(256), 0, stream>>>(aout, wob, pout);
  k_red     <<<dim3(2048),     dim3(256), 0, stream>>>(pout, d_out, flag);
}